// Round 12
// baseline (331.262 us; speedup 1.0000x reference)
//
#include <hip/hip_runtime.h>
#include <hip/hip_fp16.h>

#define NG 16     // num_graphs (fixed by problem)
#define D 64      // feature width at every aggregation point
#define SLOT 32   // CSR slots/node; max in-degree ~Poisson(8.5), P(>=32)~1e-11
#define INP 68    // padded LDS row stride (D+4): float4-aligned, conflict-free
#define SCOL 36   // padded col stride (ints): slot*36*4B -> bank 4*slot, conflict-free
#define NPB 32    // nodes per block (256 threads, 8 lanes/node)

union HF4 { float4 f4; __half2 h2[4]; };
union HF2 { float2 f2; __half2 h2[2]; };

// ---------------------------------------------------------------------------
// fp32 -> fp16 conversion (x table), float4 -> half4 per thread.
// ---------------------------------------------------------------------------
__global__ void to_half_kernel(const float* __restrict__ in,
                               float2* __restrict__ out, int n4) {
  int t = blockIdx.x * 256 + threadIdx.x;
  if (t < n4) {
    float4 v = ((const float4*)in)[t];
    HF2 u;
    u.h2[0] = __floats2half2_rn(v.x, v.y);
    u.h2[1] = __floats2half2_rn(v.z, v.w);
    out[t] = u.f2;
  }
}

// ---------------------------------------------------------------------------
// Build fixed-stride CSR by destination. 2 edges/thread, int2 loads.
// ---------------------------------------------------------------------------
__global__ void build_csr_kernel(const int* __restrict__ ei,
                                 int* __restrict__ fill,
                                 int* __restrict__ col,
                                 int E, int per, int tmul) {
  int e = 2 * (blockIdx.x * 256 + threadIdx.x);
  if (e >= E) return;
  int2 s2 = *(const int2*)(ei + e);
  int2 d2 = *(const int2*)(ei + E + e);
#pragma unroll
  for (int i = 0; i < 2; i++) {
    int ee = e + i;
    int src = i ? s2.y : s2.x;
    int dst = i ? d2.y : d2.x;
    int thr = (ee / per) * tmul;          // compiler magic-div
    if (src >= thr && dst >= thr) {
      int k = atomicAdd(&fill[dst], 1);
      if (k < SLOT) col[dst * SLOT + k] = src;
    }
  }
}

// Tree-reduce rows 0..15 (+16..31 as second half) of s_in down to row 0 /
// row 16. 64 float columns per half, float4 per lane.
__device__ __forceinline__ void tree_reduce_2x16(float* s_in, int tid) {
#pragma unroll
  for (int s = 8; s >= 1; s >>= 1) {
    if (tid < 32 * s) {
      int h = tid / (16 * s);          // 0 = first half, 1 = second half
      int r = (tid / 16) % s;
      int qq = tid & 15;
      float4* a = (float4*)&s_in[(h * 16 + r) * INP + qq * 4];
      const float4 b = *(const float4*)&s_in[(h * 16 + r + s) * INP + qq * 4];
      a->x += b.x; a->y += b.y; a->z += b.z; a->w += b.w;
    }
    __syncthreads();
  }
}

// ---------------------------------------------------------------------------
// Fused layer: fp16 gather + (optional BN fold) + fp32 MLP + epilogue.
//  EPI==1 (layer 1): store h as fp16 to `out2`, block-reduce BN stats.
//  EPI==2 (layer 2): no per-node store; per-graph pool sums + sumsq + counts.
// Block = 256 threads, 32 nodes (N%32==0 -> 3125 exact blocks).
//  Phase A0: stage the block's col lists (4 KB) + degrees into LDS with
//    coalesced int4 loads -> removes the dependent col-load from every
//    node's gather chain (R11 lesson: latency-, not BW-bound).
//  Phase A: 8 lanes/node, float4 fp16-row gathers, x8 in flight.
//  Phase B: thread (q,r2) -> nodes {2r2,2r2+1}; stage-1 mids in registers,
//    stage-2 via 16-lane __shfl; Wa+Wb in LDS as fp16.
// __launch_bounds__(256,4): >=4 waves/EU, VGPR cap 128 (no spill; R5/R6).
// ---------------------------------------------------------------------------
template <int MID, bool FOLD_BN, int EPI>
__global__ __launch_bounds__(256, 4) void fused_layer_kernel(
    const float4* __restrict__ feat4,   // fp16 table, 8 float4/row
    const int* __restrict__ col, const int* __restrict__ deg,
    const float* __restrict__ bn_sum, const float* __restrict__ bn_sq,
    const float* __restrict__ bn_gamma, const float* __restrict__ bn_beta,
    float invN,
    const float* __restrict__ Wa, const float* __restrict__ ba,
    const float* __restrict__ Wb, const float* __restrict__ bb,
    float2* __restrict__ out2,          // EPI==1 only (fp16 rows)
    const int* __restrict__ batch,      // EPI==2 only
    float* __restrict__ st_sum,         // EPI==1: sum[64]; EPI==2: pool[NG*64]
    float* __restrict__ st_sq,          // sumsq[64]
    float* __restrict__ cnt,            // EPI==2 only
    int N) {
  __shared__ float s_in[NPB * INP];
  __shared__ __half s_Wa[D * MID];
  __shared__ __half s_Wb[MID * D];
  __shared__ int s_col[NPB * SCOL];
  __shared__ int s_deg[NPB];
  __shared__ float s_bna[FOLD_BN ? D : 1];
  __shared__ float s_bnb[FOLD_BN ? D : 1];
  __shared__ int s_cnt[2];

  int tid = threadIdx.x;
  int base = blockIdx.x * NPB;

  // ---- Stage weights (fp16), col lists, degrees ----
  {
    const float4* wa4 = (const float4*)Wa;
    const float4* wb4 = (const float4*)Wb;
    __half2* sa2 = (__half2*)s_Wa;
    __half2* sb2 = (__half2*)s_Wb;
    constexpr int NW = D * MID / 4;
#pragma unroll
    for (int i = tid; i < NW; i += 256) {
      float4 a = wa4[i];
      float4 b = wb4[i];
      sa2[2 * i + 0] = __floats2half2_rn(a.x, a.y);
      sa2[2 * i + 1] = __floats2half2_rn(a.z, a.w);
      sb2[2 * i + 0] = __floats2half2_rn(b.x, b.y);
      sb2[2 * i + 1] = __floats2half2_rn(b.z, b.w);
    }
    // col: block's region is NPB*SLOT = 1024 ints = 256 int4s, one per thread
    int4 c4 = ((const int4*)(col + (size_t)base * SLOT))[tid];
    int slot = tid >> 3, j4 = tid & 7;
    *(int4*)&s_col[slot * SCOL + j4 * 4] = c4;
    if (tid < NPB) {
      int node = base + tid;
      s_deg[tid] = (node < N) ? deg[node] : 0;
    }
  }
  if (FOLD_BN && tid < D) {
    float mean = bn_sum[tid] * invN;
    float var = bn_sq[tid] * invN - mean * mean;
    float av = bn_gamma[tid] * rsqrtf(var + 1e-5f);
    s_bna[tid] = av;
    s_bnb[tid] = bn_beta[tid] - mean * av;
  }
  if (EPI == 2 && tid < 2) s_cnt[tid] = 0;
  __syncthreads();

  // ---- Phase A: 8 lanes/node fp16 gather (indices from LDS) ----
  {
    int slot = tid >> 3;          // 0..31
    int q8 = tid & 7;             // lane covers features 8*q8 .. 8*q8+7
    int node = base + slot;
    if (node < N) {
      int d = min(s_deg[slot], SLOT);
      const int* cl = &s_col[slot * SCOL];
      float acc[8];
      {
        HF4 s; s.f4 = feat4[(size_t)node * 8 + q8];   // self term
#pragma unroll
        for (int i = 0; i < 4; i++) {
          float2 f = __half22float2(s.h2[i]);
          acc[2 * i] = f.x; acc[2 * i + 1] = f.y;
        }
      }
      int j = 0;
      for (; j + 8 <= d; j += 8) {        // 8 independent row loads in flight
        int4 sa = *(const int4*)(cl + j);
        int4 sb = *(const int4*)(cl + j + 4);
        HF4 u0, u1, u2, u3, u4, u5, u6, u7;
        u0.f4 = feat4[(size_t)sa.x * 8 + q8];
        u1.f4 = feat4[(size_t)sa.y * 8 + q8];
        u2.f4 = feat4[(size_t)sa.z * 8 + q8];
        u3.f4 = feat4[(size_t)sa.w * 8 + q8];
        u4.f4 = feat4[(size_t)sb.x * 8 + q8];
        u5.f4 = feat4[(size_t)sb.y * 8 + q8];
        u6.f4 = feat4[(size_t)sb.z * 8 + q8];
        u7.f4 = feat4[(size_t)sb.w * 8 + q8];
#pragma unroll
        for (int i = 0; i < 4; i++) {
          float2 f0 = __half22float2(u0.h2[i]), f1 = __half22float2(u1.h2[i]);
          float2 f2 = __half22float2(u2.h2[i]), f3 = __half22float2(u3.h2[i]);
          float2 f4 = __half22float2(u4.h2[i]), f5 = __half22float2(u5.h2[i]);
          float2 f6 = __half22float2(u6.h2[i]), f7 = __half22float2(u7.h2[i]);
          acc[2 * i]     += (f0.x + f1.x + f2.x + f3.x) + (f4.x + f5.x + f6.x + f7.x);
          acc[2 * i + 1] += (f0.y + f1.y + f2.y + f3.y) + (f4.y + f5.y + f6.y + f7.y);
        }
      }
      if (j + 4 <= d) {
        int4 sa = *(const int4*)(cl + j);
        HF4 u0, u1, u2, u3;
        u0.f4 = feat4[(size_t)sa.x * 8 + q8];
        u1.f4 = feat4[(size_t)sa.y * 8 + q8];
        u2.f4 = feat4[(size_t)sa.z * 8 + q8];
        u3.f4 = feat4[(size_t)sa.w * 8 + q8];
#pragma unroll
        for (int i = 0; i < 4; i++) {
          float2 f0 = __half22float2(u0.h2[i]), f1 = __half22float2(u1.h2[i]);
          float2 f2 = __half22float2(u2.h2[i]), f3 = __half22float2(u3.h2[i]);
          acc[2 * i]     += f0.x + f1.x + f2.x + f3.x;
          acc[2 * i + 1] += f0.y + f1.y + f2.y + f3.y;
        }
        j += 4;
      }
      for (; j < d; j++) {
        HF4 u; u.f4 = feat4[(size_t)cl[j] * 8 + q8];
#pragma unroll
        for (int i = 0; i < 4; i++) {
          float2 f = __half22float2(u.h2[i]);
          acc[2 * i] += f.x; acc[2 * i + 1] += f.y;
        }
      }
      if (FOLD_BN) {
        float dp = (float)(d + 1);
        int c = q8 * 8;
#pragma unroll
        for (int i = 0; i < 8; i++)
          acc[i] = s_bna[c + i] * acc[i] + dp * s_bnb[c + i];
      }
      *(float4*)&s_in[slot * INP + q8 * 8] =
          make_float4(acc[0], acc[1], acc[2], acc[3]);
      *(float4*)&s_in[slot * INP + q8 * 8 + 4] =
          make_float4(acc[4], acc[5], acc[6], acc[7]);
    }
  }
  __syncthreads();

  // ---- Phase B: register-tiled MLP (fp32 math, fp16 LDS weights) ----
  int q = tid & 15;               // lane within 16-group (output cols 4q..4q+3)
  int r2 = tid >> 4;              // 0..15 -> nodes 2r2, 2r2+1
  int n0 = 2 * r2, n1 = n0 + 1;
  int node0 = base + n0, node1 = base + n1;
  constexpr int C1 = MID / 16;    // stage-1 cols per thread (2 or 4)
  float4 o0, o1;
  {
    float acc0[C1], acc1[C1];
#pragma unroll
    for (int u = 0; u < C1; u++) { acc0[u] = ba[q * C1 + u]; acc1[u] = acc0[u]; }
#pragma unroll 4
    for (int j = 0; j < D; j++) {
      float v0 = s_in[n0 * INP + j];
      float v1 = s_in[n1 * INP + j];
      if constexpr (C1 == 2) {
        float2 w = __half22float2(((const __half2*)s_Wa)[j * 16 + q]);
        acc0[0] += v0 * w.x; acc0[1] += v0 * w.y;
        acc1[0] += v1 * w.x; acc1[1] += v1 * w.y;
      } else {
        HF2 u; u.f2 = ((const float2*)s_Wa)[j * 16 + q];
        float2 wA = __half22float2(u.h2[0]);
        float2 wB = __half22float2(u.h2[1]);
        acc0[0] += v0 * wA.x; acc0[1] += v0 * wA.y;
        acc0[2] += v0 * wB.x; acc0[3] += v0 * wB.y;
        acc1[0] += v1 * wA.x; acc1[1] += v1 * wA.y;
        acc1[2] += v1 * wB.x; acc1[3] += v1 * wB.y;
      }
    }
#pragma unroll
    for (int u = 0; u < C1; u++) {
      acc0[u] = fmaxf(acc0[u], 0.f);
      acc1[u] = fmaxf(acc1[u], 0.f);
    }

    // stage 2: cols 4q..4q+3; mid[k] owner lane = k/C1, reg = k%C1
    o0 = *(const float4*)(bb + q * 4);
    o1 = o0;
#pragma unroll 8
    for (int k = 0; k < MID; k++) {
      float m0 = __shfl(acc0[k % C1], k / C1, 16);
      float m1 = __shfl(acc1[k % C1], k / C1, 16);
      HF2 u; u.f2 = ((const float2*)s_Wb)[k * 16 + q];
      float2 wA = __half22float2(u.h2[0]);
      float2 wB = __half22float2(u.h2[1]);
      o0.x += m0 * wA.x; o0.y += m0 * wA.y; o0.z += m0 * wB.x; o0.w += m0 * wB.y;
      o1.x += m1 * wA.x; o1.y += m1 * wA.y; o1.z += m1 * wB.x; o1.w += m1 * wB.y;
    }
    o0.x = fmaxf(o0.x, 0.f); o0.y = fmaxf(o0.y, 0.f);
    o0.z = fmaxf(o0.z, 0.f); o0.w = fmaxf(o0.w, 0.f);
    o1.x = fmaxf(o1.x, 0.f); o1.y = fmaxf(o1.y, 0.f);
    o1.z = fmaxf(o1.z, 0.f); o1.w = fmaxf(o1.w, 0.f);
    if (EPI == 1) {
      if (node0 < N) {
        HF2 u;
        u.h2[0] = __floats2half2_rn(o0.x, o0.y);
        u.h2[1] = __floats2half2_rn(o0.z, o0.w);
        out2[(size_t)node0 * 16 + q] = u.f2;
      }
      if (node1 < N) {
        HF2 u;
        u.h2[0] = __floats2half2_rn(o1.x, o1.y);
        u.h2[1] = __floats2half2_rn(o1.z, o1.w);
        out2[(size_t)node1 * 16 + q] = u.f2;
      }
    }
    if (node0 >= N) o0 = make_float4(0.f, 0.f, 0.f, 0.f);
    if (node1 >= N) o1 = make_float4(0.f, 0.f, 0.f, 0.f);
  }

  if (EPI == 1) {
    // ---- BN-stats epilogue: rows 0..15 sums, rows 16..31 squares ----
    __syncthreads();   // all s_in reads done; reuse s_in as reduce buffer
    *(float4*)&s_in[r2 * INP + q * 4] =
        make_float4(o0.x + o1.x, o0.y + o1.y, o0.z + o1.z, o0.w + o1.w);
    *(float4*)&s_in[(16 + r2) * INP + q * 4] =
        make_float4(o0.x * o0.x + o1.x * o1.x, o0.y * o0.y + o1.y * o1.y,
                    o0.z * o0.z + o1.z * o1.z, o0.w * o0.w + o1.w * o1.w);
    __syncthreads();
    tree_reduce_2x16(s_in, tid);
    if (tid < D) {
      atomicAdd(&st_sum[tid], s_in[tid]);
      atomicAdd(&st_sq[tid], s_in[16 * INP + tid]);
    }
  }

  if (EPI == 2) {
    // ---- Pool epilogue: <=2 graphs per 32-node block (sorted batch) ----
    int b0 = (node0 < N) ? batch[node0] : -1;
    int b1 = (node1 < N) ? batch[node1] : -1;
    int g_lo = batch[base];
    int g_hi = batch[min(base + NPB - 1, N - 1)];

    __syncthreads();   // s_in reads done; s_cnt init visible
    // ONLY q==0: the 16 q-lanes of an r2-group share the same two nodes.
    if (q == 0) {
      atomicAdd(&s_cnt[0], (b0 == g_lo ? 1 : 0) + (b1 == g_lo ? 1 : 0));
      if (g_hi != g_lo)
        atomicAdd(&s_cnt[1], (b0 == g_hi ? 1 : 0) + (b1 == g_hi ? 1 : 0));
    }

    float w0 = (b0 == g_lo) ? 1.f : 0.f;
    float w1 = (b1 == g_lo) ? 1.f : 0.f;
    *(float4*)&s_in[r2 * INP + q * 4] =
        make_float4(w0 * o0.x + w1 * o1.x, w0 * o0.y + w1 * o1.y,
                    w0 * o0.z + w1 * o1.z, w0 * o0.w + w1 * o1.w);
    *(float4*)&s_in[(16 + r2) * INP + q * 4] =
        make_float4(o0.x * o0.x + o1.x * o1.x, o0.y * o0.y + o1.y * o1.y,
                    o0.z * o0.z + o1.z * o1.z, o0.w * o0.w + o1.w * o1.w);
    __syncthreads();
    tree_reduce_2x16(s_in, tid);
    if (tid < D) {
      atomicAdd(&st_sum[g_lo * D + tid], s_in[tid]);
      atomicAdd(&st_sq[tid], s_in[16 * INP + tid]);
    }
    if (tid == 0) atomicAdd(&cnt[g_lo], (float)s_cnt[0]);

    if (g_hi != g_lo) {   // block-uniform branch
      __syncthreads();
      float u0 = (b0 == g_hi) ? 1.f : 0.f;
      float u1 = (b1 == g_hi) ? 1.f : 0.f;
      *(float4*)&s_in[r2 * INP + q * 4] =
          make_float4(u0 * o0.x + u1 * o1.x, u0 * o0.y + u1 * o1.y,
                      u0 * o0.z + u1 * o1.z, u0 * o0.w + u1 * o1.w);
      *(float4*)&s_in[(16 + r2) * INP + q * 4] = make_float4(0.f, 0.f, 0.f, 0.f);
      __syncthreads();
      tree_reduce_2x16(s_in, tid);
      if (tid < D) atomicAdd(&st_sum[g_hi * D + tid], s_in[tid]);
      if (tid == 0) atomicAdd(&cnt[g_hi], (float)s_cnt[1]);
    }
  }
}

// ---------------------------------------------------------------------------
// Final: BN2 coeffs from (Σ_g pool, sq) + fused affine + mean divide.
// ---------------------------------------------------------------------------
__global__ void final_kernel(const float* __restrict__ pool,
                             const float* __restrict__ cnt,
                             const float* __restrict__ sq,
                             const float* __restrict__ gamma,
                             const float* __restrict__ beta,
                             float invN, float* __restrict__ out) {
  int c = threadIdx.x;   // 64 threads
  float s = 0.f;
#pragma unroll
  for (int g = 0; g < NG; g++) s += pool[g * D + c];
  float mean = s * invN;
  float var = sq[c] * invN - mean * mean;
  float a = gamma[c] * rsqrtf(var + 1e-5f);
  float b = beta[c] - mean * a;
#pragma unroll
  for (int g = 0; g < NG; g++) {
    float n = cnt[g];
    out[g * D + c] = (a * pool[g * D + c] + n * b) / fmaxf(n, 1.f);
  }
}

extern "C" void kernel_launch(void* const* d_in, const int* in_sizes, int n_in,
                              void* d_out, int out_size, void* d_ws, size_t ws_size,
                              hipStream_t stream) {
  const float* x   = (const float*)d_in[0];
  const int* ei    = (const int*)d_in[1];
  const int* batch = (const int*)d_in[2];
  const float* W1a = (const float*)d_in[5];
  const float* b1a = (const float*)d_in[6];
  const float* W1b = (const float*)d_in[7];
  const float* b1b = (const float*)d_in[8];
  const float* g1  = (const float*)d_in[9];
  const float* be1 = (const float*)d_in[10];
  const float* W2a = (const float*)d_in[11];
  const float* b2a = (const float*)d_in[12];
  const float* W2b = (const float*)d_in[13];
  const float* b2b = (const float*)d_in[14];
  const float* g2  = (const float*)d_in[15];
  const float* be2 = (const float*)d_in[16];

  int N = in_sizes[0] / D;        // 100000
  int E = in_sizes[1] / 2;        // 1600000
  int per = E / NG;               // 100000
  int tmul = N / NG;              // 6250
  float invN = 1.f / (float)N;

  float* ws = (float*)d_ws;
  size_t ndh = (size_t)N * D / 2;        // word count of one fp16 N x D table
  float* h1h = ws;                       // h1 (pre-BN) fp16 table
  float* xh  = ws + ndh;                 // x fp16 table
  int*   col = (int*)(ws + 2 * ndh);     // CSR src lists (N*SLOT ints)
  float* stats = ws + 2 * ndh + (size_t)N * SLOT;
  float* sum1 = stats;                   // 64
  float* sq1  = stats + 64;              // 64
  float* pool = stats + 128;             // 16*64
  float* cnt  = stats + 128 + NG * D;    // 16
  float* sq2  = stats + 144 + NG * D;    // 64
  int*   fill = (int*)(stats + 208 + NG * D);  // N ints (degree counts)

  // Zero stats + fill (contiguous, ~0.4 MB) in one shot.
  hipMemsetAsync(stats, 0, (208 + NG * D + N) * sizeof(float), stream);

  // x -> fp16 table
  int n4 = N * D / 4;
  to_half_kernel<<<(n4 + 255) / 256, 256, 0, stream>>>(x, (float2*)xh, n4);

  build_csr_kernel<<<(E / 2 + 255) / 256, 256, 0, stream>>>(ei, fill, col, E, per, tmul);

  int fblocks = (N + NPB - 1) / NPB;   // 3125 exact

  // Layer 1: gather(xh) + MLP1 -> h1h (fp16, pre-BN) + BN1-stats epilogue
  fused_layer_kernel<32, false, 1><<<fblocks, 256, 0, stream>>>(
      (const float4*)xh, col, fill, nullptr, nullptr, nullptr, nullptr, invN,
      W1a, b1a, W1b, b1b, (float2*)h1h, nullptr, sum1, sq1, nullptr, N);

  // Layer 2: BN1 folded into gather input; pool + sumsq epilogue (no h2)
  fused_layer_kernel<64, true, 2><<<fblocks, 256, 0, stream>>>(
      (const float4*)h1h, col, fill, sum1, sq1, g1, be1, invN,
      W2a, b2a, W2b, b2b, nullptr, batch, pool, sq2, cnt, N);

  // BN2 coeffs + affine + mean.
  final_kernel<<<1, 64, 0, stream>>>(pool, cnt, sq2, g2, be2, invN, (float*)d_out);
}

// Round 13
// 264.281 us; speedup vs baseline: 1.2534x; 1.2534x over previous
//
#include <hip/hip_runtime.h>
#include <hip/hip_fp16.h>

#define NG 16     // num_graphs (fixed by problem)
#define D 64      // feature width at every aggregation point
#define SLOT 32   // CSR slots/node; max in-degree ~Poisson(8.5), P(>=32)~1e-11
#define INP 68    // padded LDS row stride (D+4): float4-aligned, conflict-free
#define NPB 64    // nodes per block (512 threads, 8 lanes/node)

// fp16 feature rows: 64 halfs = 128 B = 8 float4s. 8 lanes/node, 16 B/lane.
// Tables have N+1 rows; row N is all-zero (gather pad target).
union HF4 { float4 f4; __half2 h2[4]; };
union HF2 { float2 f2; __half2 h2[2]; };

// ---------------------------------------------------------------------------
// fp32 -> fp16 conversion (x table) + zero the pad rows of both tables.
// ---------------------------------------------------------------------------
__global__ void to_half_kernel(const float* __restrict__ in,
                               float2* __restrict__ out, int n4,
                               float4* __restrict__ xz,   // xh row N (8 float4)
                               float4* __restrict__ hz) { // h1h row N (8 float4)
  int t = blockIdx.x * 256 + threadIdx.x;
  if (blockIdx.x == 0 && threadIdx.x < 16) {
    float4 z = make_float4(0.f, 0.f, 0.f, 0.f);
    if (threadIdx.x < 8) xz[threadIdx.x] = z;
    else hz[threadIdx.x - 8] = z;
  }
  if (t < n4) {
    float4 v = ((const float4*)in)[t];
    HF2 u;
    u.h2[0] = __floats2half2_rn(v.x, v.y);
    u.h2[1] = __floats2half2_rn(v.z, v.w);
    out[t] = u.f2;
  }
}

// ---------------------------------------------------------------------------
// Build fixed-stride CSR by destination. One int atomic per VALID edge.
// ---------------------------------------------------------------------------
__global__ void build_csr_kernel(const int* __restrict__ ei,
                                 int* __restrict__ fill,
                                 int* __restrict__ col,
                                 int E, int per, int tmul) {
  int e = blockIdx.x * blockDim.x + threadIdx.x;
  if (e >= E) return;
  int src = ei[e];
  int dst = ei[E + e];
  int g = e / per;            // compiler magic-div
  int thr = g * tmul;
  if (src >= thr && dst >= thr) {
    int k = atomicAdd(&fill[dst], 1);
    if (k < SLOT) col[dst * SLOT + k] = src;   // clamp is paranoia-only
  }
}

// Tree-reduce rows 0..31 (+32..63 as a second half) of s_in down to row 0 /
// row 32. 64 float columns per half, float4 per lane.
__device__ __forceinline__ void tree_reduce_2x32(float* s_in, int tid) {
#pragma unroll
  for (int s = 16; s >= 1; s >>= 1) {
    if (tid < 32 * s) {
      int h = tid / (16 * s);          // 0 = first half, 1 = second half
      int r = (tid / 16) % s;
      int qq = tid & 15;
      float4* a = (float4*)&s_in[(h * 32 + r) * INP + qq * 4];
      const float4 b = *(const float4*)&s_in[(h * 32 + r + s) * INP + qq * 4];
      a->x += b.x; a->y += b.y; a->z += b.z; a->w += b.w;
    }
    __syncthreads();
  }
}

// ---------------------------------------------------------------------------
// Fused layer: fp16 gather + (optional BN fold) + fp32 MLP + epilogue.
//  EPI==1 (layer 1): store h as fp16 to `out2`, block-reduce BN stats.
//  EPI==2 (layer 2): no per-node store; per-graph pool sums + sumsq + counts.
// Block = 512 threads, 64 nodes (R12 lesson: 256-thr blocks doubled per-block
// weight-staging overhead and regressed; this is the measured-best shape).
//  Phase A: 8 lanes/node, float4 fp16-row gathers, rounds of EXACTLY 8
//    unconditional loads — pad indices redirect to zero row N, so d<=8 nodes
//    (86%) finish the whole gather in ONE latency trip (R11's 4+tail chain
//    was 3 dependent trips for the average node).
//  Phase B: thread (q,r2) -> nodes {2r2,2r2+1}; stage-1 mids in registers,
//    stage-2 via 16-lane __shfl; Wa+Wb in LDS as fp16.
// __launch_bounds__ 2nd arg (empirical, 512-thr blocks): VGPR cap = 256/arg.
//   arg=8 -> 32 (R5 spill), arg=4 -> 64 (R6 spill), arg=2 -> 128 (safe).
// ---------------------------------------------------------------------------
template <int MID, bool FOLD_BN, int EPI>
__global__ __launch_bounds__(512, 2) void fused_layer_kernel(
    const float4* __restrict__ feat4,   // fp16 table, 8 float4/row, N+1 rows
    const int* __restrict__ col, const int* __restrict__ deg,
    const float* __restrict__ bn_sum, const float* __restrict__ bn_sq,
    const float* __restrict__ bn_gamma, const float* __restrict__ bn_beta,
    float invN,
    const float* __restrict__ Wa, const float* __restrict__ ba,
    const float* __restrict__ Wb, const float* __restrict__ bb,
    float2* __restrict__ out2,          // EPI==1 only (fp16 rows)
    const int* __restrict__ batch,      // EPI==2 only
    float* __restrict__ st_sum,         // EPI==1: sum[64]; EPI==2: pool[NG*64]
    float* __restrict__ st_sq,          // sumsq[64]
    float* __restrict__ cnt,            // EPI==2 only
    int N) {
  __shared__ float s_in[NPB * INP];
  __shared__ __half s_Wa[D * MID];
  __shared__ __half s_Wb[MID * D];
  __shared__ float s_bna[FOLD_BN ? D : 1];
  __shared__ float s_bnb[FOLD_BN ? D : 1];
  __shared__ int s_cnt[2];

  int tid = threadIdx.x;

  // Stage Wa+Wb as fp16 (coalesced float4 reads, once per block).
  {
    const float4* wa4 = (const float4*)Wa;
    const float4* wb4 = (const float4*)Wb;
    __half2* sa2 = (__half2*)s_Wa;
    __half2* sb2 = (__half2*)s_Wb;
    constexpr int NW = D * MID / 4;
#pragma unroll
    for (int i = tid; i < NW; i += 512) {
      float4 a = wa4[i];
      float4 b = wb4[i];
      sa2[2 * i + 0] = __floats2half2_rn(a.x, a.y);
      sa2[2 * i + 1] = __floats2half2_rn(a.z, a.w);
      sb2[2 * i + 0] = __floats2half2_rn(b.x, b.y);
      sb2[2 * i + 1] = __floats2half2_rn(b.z, b.w);
    }
  }
  if (FOLD_BN && tid < D) {
    float mean = bn_sum[tid] * invN;
    float var = bn_sq[tid] * invN - mean * mean;
    float av = bn_gamma[tid] * rsqrtf(var + 1e-5f);
    s_bna[tid] = av;
    s_bnb[tid] = bn_beta[tid] - mean * av;
  }
  if (EPI == 2 && tid < 2) s_cnt[tid] = 0;
  __syncthreads();

  int base = blockIdx.x * NPB;

  // ---- Phase A: 8 lanes/node fp16 gather, uniform 8-wide rounds ----
  {
    int slot = tid >> 3;          // 0..63
    int q8 = tid & 7;             // lane covers features 8*q8 .. 8*q8+7
    int node = base + slot;
    if (node < N) {
      int d = min(deg[node], SLOT);
      const int* cl = col + node * SLOT;
      float acc[8];
      {
        HF4 s; s.f4 = feat4[(size_t)node * 8 + q8];   // self term
#pragma unroll
        for (int i = 0; i < 4; i++) {
          float2 f = __half22float2(s.h2[i]);
          acc[2 * i] = f.x; acc[2 * i + 1] = f.y;
        }
      }
      int dpad = (d + 7) & ~7;    // rounds of exactly 8 unconditional loads
      for (int j = 0; j < dpad; j += 8) {
        int4 sa = *(const int4*)(cl + j);       // region is 32 ints: in-bounds
        int4 sb = *(const int4*)(cl + j + 4);
        int i0 = (j + 0 < d) ? sa.x : N;        // pad -> zero row
        int i1 = (j + 1 < d) ? sa.y : N;
        int i2 = (j + 2 < d) ? sa.z : N;
        int i3 = (j + 3 < d) ? sa.w : N;
        int i4 = (j + 4 < d) ? sb.x : N;
        int i5 = (j + 5 < d) ? sb.y : N;
        int i6 = (j + 6 < d) ? sb.z : N;
        int i7 = (j + 7 < d) ? sb.w : N;
        HF4 u0, u1, u2, u3, u4, u5, u6, u7;
        u0.f4 = feat4[(size_t)i0 * 8 + q8];
        u1.f4 = feat4[(size_t)i1 * 8 + q8];
        u2.f4 = feat4[(size_t)i2 * 8 + q8];
        u3.f4 = feat4[(size_t)i3 * 8 + q8];
        u4.f4 = feat4[(size_t)i4 * 8 + q8];
        u5.f4 = feat4[(size_t)i5 * 8 + q8];
        u6.f4 = feat4[(size_t)i6 * 8 + q8];
        u7.f4 = feat4[(size_t)i7 * 8 + q8];
#pragma unroll
        for (int i = 0; i < 4; i++) {
          float2 f0 = __half22float2(u0.h2[i]), f1 = __half22float2(u1.h2[i]);
          float2 f2 = __half22float2(u2.h2[i]), f3 = __half22float2(u3.h2[i]);
          float2 f4 = __half22float2(u4.h2[i]), f5 = __half22float2(u5.h2[i]);
          float2 f6 = __half22float2(u6.h2[i]), f7 = __half22float2(u7.h2[i]);
          acc[2 * i]     += (f0.x + f1.x + f2.x + f3.x) + (f4.x + f5.x + f6.x + f7.x);
          acc[2 * i + 1] += (f0.y + f1.y + f2.y + f3.y) + (f4.y + f5.y + f6.y + f7.y);
        }
      }
      if (FOLD_BN) {
        float dp = (float)(d + 1);
        int c = q8 * 8;
#pragma unroll
        for (int i = 0; i < 8; i++)
          acc[i] = s_bna[c + i] * acc[i] + dp * s_bnb[c + i];
      }
      *(float4*)&s_in[slot * INP + q8 * 8] =
          make_float4(acc[0], acc[1], acc[2], acc[3]);
      *(float4*)&s_in[slot * INP + q8 * 8 + 4] =
          make_float4(acc[4], acc[5], acc[6], acc[7]);
    }
  }
  __syncthreads();

  // ---- Phase B: register-tiled MLP (fp32 math, fp16 LDS weights) ----
  int q = tid & 15;               // lane within 16-group (output cols 4q..4q+3)
  int r2 = tid >> 4;              // 0..31 -> nodes 2r2, 2r2+1
  int n0 = 2 * r2, n1 = n0 + 1;
  int node0 = base + n0, node1 = base + n1;
  constexpr int C1 = MID / 16;    // stage-1 cols per thread (2 or 4)
  float4 o0, o1;
  {
    float acc0[C1], acc1[C1];
#pragma unroll
    for (int u = 0; u < C1; u++) { acc0[u] = ba[q * C1 + u]; acc1[u] = acc0[u]; }
#pragma unroll 4
    for (int j = 0; j < D; j++) {
      float v0 = s_in[n0 * INP + j];
      float v1 = s_in[n1 * INP + j];
      if constexpr (C1 == 2) {
        float2 w = __half22float2(((const __half2*)s_Wa)[j * 16 + q]);
        acc0[0] += v0 * w.x; acc0[1] += v0 * w.y;
        acc1[0] += v1 * w.x; acc1[1] += v1 * w.y;
      } else {
        HF2 u; u.f2 = ((const float2*)s_Wa)[j * 16 + q];
        float2 wA = __half22float2(u.h2[0]);
        float2 wB = __half22float2(u.h2[1]);
        acc0[0] += v0 * wA.x; acc0[1] += v0 * wA.y;
        acc0[2] += v0 * wB.x; acc0[3] += v0 * wB.y;
        acc1[0] += v1 * wA.x; acc1[1] += v1 * wA.y;
        acc1[2] += v1 * wB.x; acc1[3] += v1 * wB.y;
      }
    }
#pragma unroll
    for (int u = 0; u < C1; u++) {
      acc0[u] = fmaxf(acc0[u], 0.f);
      acc1[u] = fmaxf(acc1[u], 0.f);
    }

    // stage 2: cols 4q..4q+3; mid[k] owner lane = k/C1, reg = k%C1
    o0 = *(const float4*)(bb + q * 4);
    o1 = o0;
#pragma unroll 8
    for (int k = 0; k < MID; k++) {
      float m0 = __shfl(acc0[k % C1], k / C1, 16);
      float m1 = __shfl(acc1[k % C1], k / C1, 16);
      HF2 u; u.f2 = ((const float2*)s_Wb)[k * 16 + q];
      float2 wA = __half22float2(u.h2[0]);
      float2 wB = __half22float2(u.h2[1]);
      o0.x += m0 * wA.x; o0.y += m0 * wA.y; o0.z += m0 * wB.x; o0.w += m0 * wB.y;
      o1.x += m1 * wA.x; o1.y += m1 * wA.y; o1.z += m1 * wB.x; o1.w += m1 * wB.y;
    }
    o0.x = fmaxf(o0.x, 0.f); o0.y = fmaxf(o0.y, 0.f);
    o0.z = fmaxf(o0.z, 0.f); o0.w = fmaxf(o0.w, 0.f);
    o1.x = fmaxf(o1.x, 0.f); o1.y = fmaxf(o1.y, 0.f);
    o1.z = fmaxf(o1.z, 0.f); o1.w = fmaxf(o1.w, 0.f);
    if (EPI == 1) {
      if (node0 < N) {
        HF2 u;
        u.h2[0] = __floats2half2_rn(o0.x, o0.y);
        u.h2[1] = __floats2half2_rn(o0.z, o0.w);
        out2[(size_t)node0 * 16 + q] = u.f2;
      }
      if (node1 < N) {
        HF2 u;
        u.h2[0] = __floats2half2_rn(o1.x, o1.y);
        u.h2[1] = __floats2half2_rn(o1.z, o1.w);
        out2[(size_t)node1 * 16 + q] = u.f2;
      }
    }
    if (node0 >= N) o0 = make_float4(0.f, 0.f, 0.f, 0.f);
    if (node1 >= N) o1 = make_float4(0.f, 0.f, 0.f, 0.f);
  }

  if (EPI == 1) {
    // ---- BN-stats epilogue: block tree-reduce sum + sumsq, 128 atomics ----
    __syncthreads();   // all s_in reads done; reuse s_in as reduce buffer
    *(float4*)&s_in[r2 * INP + q * 4] =
        make_float4(o0.x + o1.x, o0.y + o1.y, o0.z + o1.z, o0.w + o1.w);
    *(float4*)&s_in[(32 + r2) * INP + q * 4] =
        make_float4(o0.x * o0.x + o1.x * o1.x, o0.y * o0.y + o1.y * o1.y,
                    o0.z * o0.z + o1.z * o1.z, o0.w * o0.w + o1.w * o1.w);
    __syncthreads();
    tree_reduce_2x32(s_in, tid);
    if (tid < D) {
      atomicAdd(&st_sum[tid], s_in[tid]);
      atomicAdd(&st_sq[tid], s_in[32 * INP + tid]);
    }
  }

  if (EPI == 2) {
    // ---- Pool epilogue: <=2 graphs per 64-node block (sorted batch) ----
    int b0 = (node0 < N) ? batch[node0] : -1;
    int b1 = (node1 < N) ? batch[node1] : -1;
    int g_lo = batch[base];
    int g_hi = batch[min(base + NPB - 1, N - 1)];

    __syncthreads();   // s_in reads done; s_cnt init visible
    // ONLY q==0: the 16 q-lanes of an r2-group share the same two nodes.
    if (q == 0) {
      atomicAdd(&s_cnt[0], (b0 == g_lo ? 1 : 0) + (b1 == g_lo ? 1 : 0));
      if (g_hi != g_lo)
        atomicAdd(&s_cnt[1], (b0 == g_hi ? 1 : 0) + (b1 == g_hi ? 1 : 0));
    }

    float w0 = (b0 == g_lo) ? 1.f : 0.f;
    float w1 = (b1 == g_lo) ? 1.f : 0.f;
    *(float4*)&s_in[r2 * INP + q * 4] =
        make_float4(w0 * o0.x + w1 * o1.x, w0 * o0.y + w1 * o1.y,
                    w0 * o0.z + w1 * o1.z, w0 * o0.w + w1 * o1.w);
    *(float4*)&s_in[(32 + r2) * INP + q * 4] =
        make_float4(o0.x * o0.x + o1.x * o1.x, o0.y * o0.y + o1.y * o1.y,
                    o0.z * o0.z + o1.z * o1.z, o0.w * o0.w + o1.w * o1.w);
    __syncthreads();
    tree_reduce_2x32(s_in, tid);
    if (tid < D) {
      atomicAdd(&st_sum[g_lo * D + tid], s_in[tid]);
      atomicAdd(&st_sq[tid], s_in[32 * INP + tid]);
    }
    if (tid == 0) atomicAdd(&cnt[g_lo], (float)s_cnt[0]);

    if (g_hi != g_lo) {   // block-uniform branch
      __syncthreads();
      float u0 = (b0 == g_hi) ? 1.f : 0.f;
      float u1 = (b1 == g_hi) ? 1.f : 0.f;
      *(float4*)&s_in[r2 * INP + q * 4] =
          make_float4(u0 * o0.x + u1 * o1.x, u0 * o0.y + u1 * o1.y,
                      u0 * o0.z + u1 * o1.z, u0 * o0.w + u1 * o1.w);
      *(float4*)&s_in[(32 + r2) * INP + q * 4] = make_float4(0.f, 0.f, 0.f, 0.f);
      __syncthreads();
      tree_reduce_2x32(s_in, tid);
      if (tid < D) atomicAdd(&st_sum[g_hi * D + tid], s_in[tid]);
      if (tid == 0) atomicAdd(&cnt[g_hi], (float)s_cnt[1]);
    }
  }
}

// ---------------------------------------------------------------------------
// Final: BN2 coeffs from (Σ_g pool, sq) + fused affine + mean divide.
// ---------------------------------------------------------------------------
__global__ void final_kernel(const float* __restrict__ pool,
                             const float* __restrict__ cnt,
                             const float* __restrict__ sq,
                             const float* __restrict__ gamma,
                             const float* __restrict__ beta,
                             float invN, float* __restrict__ out) {
  int c = threadIdx.x;   // 64 threads
  float s = 0.f;
#pragma unroll
  for (int g = 0; g < NG; g++) s += pool[g * D + c];
  float mean = s * invN;
  float var = sq[c] * invN - mean * mean;
  float a = gamma[c] * rsqrtf(var + 1e-5f);
  float b = beta[c] - mean * a;
#pragma unroll
  for (int g = 0; g < NG; g++) {
    float n = cnt[g];
    out[g * D + c] = (a * pool[g * D + c] + n * b) / fmaxf(n, 1.f);
  }
}

extern "C" void kernel_launch(void* const* d_in, const int* in_sizes, int n_in,
                              void* d_out, int out_size, void* d_ws, size_t ws_size,
                              hipStream_t stream) {
  const float* x   = (const float*)d_in[0];
  const int* ei    = (const int*)d_in[1];
  const int* batch = (const int*)d_in[2];
  const float* W1a = (const float*)d_in[5];
  const float* b1a = (const float*)d_in[6];
  const float* W1b = (const float*)d_in[7];
  const float* b1b = (const float*)d_in[8];
  const float* g1  = (const float*)d_in[9];
  const float* be1 = (const float*)d_in[10];
  const float* W2a = (const float*)d_in[11];
  const float* b2a = (const float*)d_in[12];
  const float* W2b = (const float*)d_in[13];
  const float* b2b = (const float*)d_in[14];
  const float* g2  = (const float*)d_in[15];
  const float* be2 = (const float*)d_in[16];

  int N = in_sizes[0] / D;        // 100000
  int E = in_sizes[1] / 2;        // 1600000
  int per = E / NG;               // 100000
  int tmul = N / NG;              // 6250
  float invN = 1.f / (float)N;

  float* ws = (float*)d_ws;
  size_t ndh = (size_t)(N + 1) * D / 2;  // fp16 table size in floats (N+1 rows)
  float* h1h = ws;                       // h1 (pre-BN) fp16 table, N+1 rows
  float* xh  = ws + ndh;                 // x fp16 table, N+1 rows
  int*   col = (int*)(ws + 2 * ndh);     // CSR src lists (N*SLOT ints)
  float* stats = ws + 2 * ndh + (size_t)N * SLOT;
  float* sum1 = stats;                   // 64
  float* sq1  = stats + 64;              // 64
  float* pool = stats + 128;             // 16*64
  float* cnt  = stats + 128 + NG * D;    // 16
  float* sq2  = stats + 144 + NG * D;    // 64
  int*   fill = (int*)(stats + 208 + NG * D);  // N ints (degree counts)

  // Zero stats + fill (contiguous, ~0.4 MB) in one shot.
  hipMemsetAsync(stats, 0, (208 + NG * D + N) * sizeof(float), stream);

  // x -> fp16 table; also zero pad-row N of both tables (ws is re-poisoned).
  int n4 = N * D / 4;
  to_half_kernel<<<(n4 + 255) / 256, 256, 0, stream>>>(
      x, (float2*)xh, n4,
      (float4*)(xh + (size_t)N * D / 2),
      (float4*)(h1h + (size_t)N * D / 2));

  build_csr_kernel<<<(E + 255) / 256, 256, 0, stream>>>(ei, fill, col, E, per, tmul);

  int fblocks = (N + NPB - 1) / NPB;   // 1563

  // Layer 1: gather(xh) + MLP1 -> h1h (fp16, pre-BN) + BN1-stats epilogue
  fused_layer_kernel<32, false, 1><<<fblocks, 512, 0, stream>>>(
      (const float4*)xh, col, fill, nullptr, nullptr, nullptr, nullptr, invN,
      W1a, b1a, W1b, b1b, (float2*)h1h, nullptr, sum1, sq1, nullptr, N);

  // Layer 2: BN1 folded into gather input; pool + sumsq epilogue (no h2)
  fused_layer_kernel<64, true, 2><<<fblocks, 512, 0, stream>>>(
      (const float4*)h1h, col, fill, sum1, sq1, g1, be1, invN,
      W2a, b2a, W2b, b2b, nullptr, batch, pool, sq2, cnt, N);

  // BN2 coeffs + affine + mean.
  final_kernel<<<1, 64, 0, stream>>>(pool, cnt, sq2, g2, be2, invN, (float*)d_out);
}

// Round 14
// 248.614 us; speedup vs baseline: 1.3324x; 1.0630x over previous
//
#include <hip/hip_runtime.h>
#include <hip/hip_fp16.h>

#define NG 16     // num_graphs (fixed by problem)
#define D 64      // feature width at every aggregation point
#define SLOT 32   // CSR slots/node; max in-degree ~Poisson(8.5), P(>=32)~1e-11
#define INP 68    // padded LDS row stride (D+4): float4-aligned, conflict-free
#define NPB 64    // nodes per block (512 threads, 8 lanes/node)

// fp16 feature rows: 64 halfs = 128 B = 8 float4s. 8 lanes/node, 16 B/lane.
// Tables have N+1 rows; row N is all-zero (gather pad target).
union HF4 { float4 f4; __half2 h2[4]; };
union HF2 { float2 f2; __half2 h2[2]; };

// float2 helpers written as explicit fmaf pairs -> LLVM can pack to
// v_pk_fma_f32 / v_pk_add_f32 (CDNA packed fp32 = the 157TF path).
__device__ __forceinline__ float2 f2fma(float2 a, float2 b, float2 c) {
  return make_float2(fmaf(a.x, b.x, c.x), fmaf(a.y, b.y, c.y));
}
__device__ __forceinline__ float2 f2add(float2 a, float2 b) {
  return make_float2(a.x + b.x, a.y + b.y);
}

// ---------------------------------------------------------------------------
// Fused prep: x->fp16 convert (t < n4) + CSR build (t < E) + pad-row zeroing.
// n4 == E == 1.6M for this problem, so one grid covers both jobs.
// fill[] must be zeroed beforehand (memset on same stream).
// ---------------------------------------------------------------------------
__global__ void prep_kernel(const float* __restrict__ x,
                            float2* __restrict__ xh, int n4,
                            float4* __restrict__ xz, float4* __restrict__ hz,
                            const int* __restrict__ ei,
                            int* __restrict__ fill, int* __restrict__ col,
                            int E, int per, int tmul) {
  int t = blockIdx.x * 256 + threadIdx.x;
  if (blockIdx.x == 0 && threadIdx.x < 16) {
    float4 z = make_float4(0.f, 0.f, 0.f, 0.f);
    if (threadIdx.x < 8) xz[threadIdx.x] = z;
    else hz[threadIdx.x - 8] = z;
  }
  if (t < n4) {
    float4 v = ((const float4*)x)[t];
    HF2 u;
    u.h2[0] = __floats2half2_rn(v.x, v.y);
    u.h2[1] = __floats2half2_rn(v.z, v.w);
    xh[t] = u.f2;
  }
  if (t < E) {
    int src = ei[t];
    int dst = ei[E + t];
    int thr = (t / per) * tmul;       // compiler magic-div
    if (src >= thr && dst >= thr) {
      int k = atomicAdd(&fill[dst], 1);
      if (k < SLOT) col[dst * SLOT + k] = src;
    }
  }
}

// Tree-reduce rows 0..31 (+32..63 as a second half) of s_in down to row 0 /
// row 32. 64 float columns per half, float4 per lane.
__device__ __forceinline__ void tree_reduce_2x32(float* s_in, int tid) {
#pragma unroll
  for (int s = 16; s >= 1; s >>= 1) {
    if (tid < 32 * s) {
      int h = tid / (16 * s);          // 0 = first half, 1 = second half
      int r = (tid / 16) % s;
      int qq = tid & 15;
      float4* a = (float4*)&s_in[(h * 32 + r) * INP + qq * 4];
      const float4 b = *(const float4*)&s_in[(h * 32 + r + s) * INP + qq * 4];
      a->x += b.x; a->y += b.y; a->z += b.z; a->w += b.w;
    }
    __syncthreads();
  }
}

// ---------------------------------------------------------------------------
// Fused layer: fp16 gather + (optional BN fold) + fp32 MLP + epilogue.
//  EPI==1 (layer 1): store h as fp16 to `out2`, block-reduce BN stats.
//  EPI==2 (layer 2): no per-node store; per-graph pool sums + sumsq + counts.
// Block = 512 threads, 64 nodes (R12: 256-thr blocks regressed).
//  Phase A: 8 lanes/node, rounds of EXACTLY 16 unconditional float4 loads
//    (pad -> zero row N). P(d>16) ~ 1e-4, so ~every wave finishes its whole
//    gather in ONE latency trip (R13's 8-wide took 2 for max-degree node).
//  Phase B: float2-packed fp32 math (targets v_pk_fma_f32); stage-1 mids in
//    registers, stage-2 via 16-lane __shfl; Wa+Wb in LDS as fp16.
// __launch_bounds__ 2nd arg (empirical, 512-thr blocks): VGPR cap = 256/arg.
//   arg=8 -> 32 (R5 spill), arg=4 -> 64 (R6 spill), arg=2 -> 128 (safe).
// ---------------------------------------------------------------------------
template <int MID, bool FOLD_BN, int EPI>
__global__ __launch_bounds__(512, 2) void fused_layer_kernel(
    const float4* __restrict__ feat4,   // fp16 table, 8 float4/row, N+1 rows
    const int* __restrict__ col, const int* __restrict__ deg,
    const float* __restrict__ bn_sum, const float* __restrict__ bn_sq,
    const float* __restrict__ bn_gamma, const float* __restrict__ bn_beta,
    float invN,
    const float* __restrict__ Wa, const float* __restrict__ ba,
    const float* __restrict__ Wb, const float* __restrict__ bb,
    float2* __restrict__ out2,          // EPI==1 only (fp16 rows)
    const int* __restrict__ batch,      // EPI==2 only
    float* __restrict__ st_sum,         // EPI==1: sum[64]; EPI==2: pool[NG*64]
    float* __restrict__ st_sq,          // sumsq[64]
    float* __restrict__ cnt,            // EPI==2 only
    int N) {
  __shared__ float s_in[NPB * INP];
  __shared__ __half s_Wa[D * MID];
  __shared__ __half s_Wb[MID * D];
  __shared__ float s_bna[FOLD_BN ? D : 1];
  __shared__ float s_bnb[FOLD_BN ? D : 1];
  __shared__ int s_cnt[2];

  int tid = threadIdx.x;

  // Stage Wa+Wb as fp16 (coalesced float4 reads, once per block).
  {
    const float4* wa4 = (const float4*)Wa;
    const float4* wb4 = (const float4*)Wb;
    __half2* sa2 = (__half2*)s_Wa;
    __half2* sb2 = (__half2*)s_Wb;
    constexpr int NW = D * MID / 4;
#pragma unroll
    for (int i = tid; i < NW; i += 512) {
      float4 a = wa4[i];
      float4 b = wb4[i];
      sa2[2 * i + 0] = __floats2half2_rn(a.x, a.y);
      sa2[2 * i + 1] = __floats2half2_rn(a.z, a.w);
      sb2[2 * i + 0] = __floats2half2_rn(b.x, b.y);
      sb2[2 * i + 1] = __floats2half2_rn(b.z, b.w);
    }
  }
  if (FOLD_BN && tid < D) {
    float mean = bn_sum[tid] * invN;
    float var = bn_sq[tid] * invN - mean * mean;
    float av = bn_gamma[tid] * rsqrtf(var + 1e-5f);
    s_bna[tid] = av;
    s_bnb[tid] = bn_beta[tid] - mean * av;
  }
  if (EPI == 2 && tid < 2) s_cnt[tid] = 0;
  __syncthreads();

  int base = blockIdx.x * NPB;

  // ---- Phase A: 8 lanes/node fp16 gather, uniform 16-wide rounds ----
  {
    int slot = tid >> 3;          // 0..63
    int q8 = tid & 7;             // lane covers features 8*q8 .. 8*q8+7
    int node = base + slot;
    if (node < N) {
      int d = min(deg[node], SLOT);
      const int* cl = col + node * SLOT;
      float2 acc[4];              // 8 features as 4 packed float2
      {
        HF4 s; s.f4 = feat4[(size_t)node * 8 + q8];   // self term
#pragma unroll
        for (int i = 0; i < 4; i++) acc[i] = __half22float2(s.h2[i]);
      }
      int dpad = (d + 15) & ~15;  // rounds of exactly 16 unconditional loads
      for (int j = 0; j < dpad; j += 16) {
        int4 sa = *(const int4*)(cl + j);       // SLOT=32: j+15 in-bounds
        int4 sb = *(const int4*)(cl + j + 4);
        int4 sc = *(const int4*)(cl + j + 8);
        int4 sd = *(const int4*)(cl + j + 12);
        int idx[16];
        idx[0]  = (j + 0  < d) ? sa.x : N;  idx[1]  = (j + 1  < d) ? sa.y : N;
        idx[2]  = (j + 2  < d) ? sa.z : N;  idx[3]  = (j + 3  < d) ? sa.w : N;
        idx[4]  = (j + 4  < d) ? sb.x : N;  idx[5]  = (j + 5  < d) ? sb.y : N;
        idx[6]  = (j + 6  < d) ? sb.z : N;  idx[7]  = (j + 7  < d) ? sb.w : N;
        idx[8]  = (j + 8  < d) ? sc.x : N;  idx[9]  = (j + 9  < d) ? sc.y : N;
        idx[10] = (j + 10 < d) ? sc.z : N;  idx[11] = (j + 11 < d) ? sc.w : N;
        idx[12] = (j + 12 < d) ? sd.x : N;  idx[13] = (j + 13 < d) ? sd.y : N;
        idx[14] = (j + 14 < d) ? sd.z : N;  idx[15] = (j + 15 < d) ? sd.w : N;
        HF4 u[16];
#pragma unroll
        for (int i = 0; i < 16; i++) u[i].f4 = feat4[(size_t)idx[i] * 8 + q8];
#pragma unroll
        for (int i = 0; i < 16; i++) {
#pragma unroll
          for (int c = 0; c < 4; c++)
            acc[c] = f2add(acc[c], __half22float2(u[i].h2[c]));
        }
      }
      if (FOLD_BN) {
        float dp = (float)(d + 1);
        int c0 = q8 * 8;
#pragma unroll
        for (int c = 0; c < 4; c++) {
          float2 a2 = *(const float2*)&s_bna[c0 + 2 * c];
          float2 b2 = *(const float2*)&s_bnb[c0 + 2 * c];
          acc[c] = f2fma(a2, acc[c], make_float2(dp * b2.x, dp * b2.y));
        }
      }
      *(float4*)&s_in[slot * INP + q8 * 8] =
          make_float4(acc[0].x, acc[0].y, acc[1].x, acc[1].y);
      *(float4*)&s_in[slot * INP + q8 * 8 + 4] =
          make_float4(acc[2].x, acc[2].y, acc[3].x, acc[3].y);
    }
  }
  __syncthreads();

  // ---- Phase B: register-tiled MLP (float2-packed fp32, fp16 LDS weights) --
  int q = tid & 15;               // lane within 16-group (output cols 4q..4q+3)
  int r2 = tid >> 4;              // 0..31 -> nodes 2r2, 2r2+1
  int n0 = 2 * r2, n1 = n0 + 1;
  int node0 = base + n0, node1 = base + n1;
  constexpr int C1 = MID / 16;    // stage-1 cols per thread (2 or 4)
  constexpr int C2 = C1 / 2;      // as packed float2 (1 or 2)
  float4 o0, o1;
  {
    float2 acc0[C2], acc1[C2];
#pragma unroll
    for (int u = 0; u < C2; u++) {
      acc0[u] = *(const float2*)&ba[q * C1 + 2 * u];
      acc1[u] = acc0[u];
    }
#pragma unroll 4
    for (int j = 0; j < D; j++) {
      float2 v0 = make_float2(s_in[n0 * INP + j], s_in[n0 * INP + j]);
      float2 v1 = make_float2(s_in[n1 * INP + j], s_in[n1 * INP + j]);
      if constexpr (C1 == 2) {
        float2 w = __half22float2(((const __half2*)s_Wa)[j * 16 + q]);
        acc0[0] = f2fma(v0, w, acc0[0]);
        acc1[0] = f2fma(v1, w, acc1[0]);
      } else {
        HF2 u; u.f2 = ((const float2*)s_Wa)[j * 16 + q];
        float2 wA = __half22float2(u.h2[0]);
        float2 wB = __half22float2(u.h2[1]);
        acc0[0] = f2fma(v0, wA, acc0[0]);
        acc0[1] = f2fma(v0, wB, acc0[1]);
        acc1[0] = f2fma(v1, wA, acc1[0]);
        acc1[1] = f2fma(v1, wB, acc1[1]);
      }
    }
#pragma unroll
    for (int u = 0; u < C2; u++) {
      acc0[u].x = fmaxf(acc0[u].x, 0.f); acc0[u].y = fmaxf(acc0[u].y, 0.f);
      acc1[u].x = fmaxf(acc1[u].x, 0.f); acc1[u].y = fmaxf(acc1[u].y, 0.f);
    }

    // stage 2: cols 4q..4q+3; mid[k] owner lane = k/C1, float2 reg (k%C1)>>1,
    // component (k%C1)&1 (k is compile-time in the unrolled loop).
    float2 o0a = *(const float2*)&bb[q * 4];
    float2 o0b = *(const float2*)&bb[q * 4 + 2];
    float2 o1a = o0a, o1b = o0b;
#pragma unroll 8
    for (int k = 0; k < MID; k++) {
      float s0 = ((k % C1) & 1) ? acc0[(k % C1) >> 1].y : acc0[(k % C1) >> 1].x;
      float s1 = ((k % C1) & 1) ? acc1[(k % C1) >> 1].y : acc1[(k % C1) >> 1].x;
      float m0 = __shfl(s0, k / C1, 16);
      float m1 = __shfl(s1, k / C1, 16);
      HF2 u; u.f2 = ((const float2*)s_Wb)[k * 16 + q];
      float2 wA = __half22float2(u.h2[0]);
      float2 wB = __half22float2(u.h2[1]);
      float2 m0f = make_float2(m0, m0);
      float2 m1f = make_float2(m1, m1);
      o0a = f2fma(m0f, wA, o0a); o0b = f2fma(m0f, wB, o0b);
      o1a = f2fma(m1f, wA, o1a); o1b = f2fma(m1f, wB, o1b);
    }
    o0 = make_float4(fmaxf(o0a.x, 0.f), fmaxf(o0a.y, 0.f),
                     fmaxf(o0b.x, 0.f), fmaxf(o0b.y, 0.f));
    o1 = make_float4(fmaxf(o1a.x, 0.f), fmaxf(o1a.y, 0.f),
                     fmaxf(o1b.x, 0.f), fmaxf(o1b.y, 0.f));
    if (EPI == 1) {
      if (node0 < N) {
        HF2 u;
        u.h2[0] = __floats2half2_rn(o0.x, o0.y);
        u.h2[1] = __floats2half2_rn(o0.z, o0.w);
        out2[(size_t)node0 * 16 + q] = u.f2;
      }
      if (node1 < N) {
        HF2 u;
        u.h2[0] = __floats2half2_rn(o1.x, o1.y);
        u.h2[1] = __floats2half2_rn(o1.z, o1.w);
        out2[(size_t)node1 * 16 + q] = u.f2;
      }
    }
    if (node0 >= N) o0 = make_float4(0.f, 0.f, 0.f, 0.f);
    if (node1 >= N) o1 = make_float4(0.f, 0.f, 0.f, 0.f);
  }

  if (EPI == 1) {
    // ---- BN-stats epilogue: block tree-reduce sum + sumsq, 128 atomics ----
    __syncthreads();   // all s_in reads done; reuse s_in as reduce buffer
    *(float4*)&s_in[r2 * INP + q * 4] =
        make_float4(o0.x + o1.x, o0.y + o1.y, o0.z + o1.z, o0.w + o1.w);
    *(float4*)&s_in[(32 + r2) * INP + q * 4] =
        make_float4(o0.x * o0.x + o1.x * o1.x, o0.y * o0.y + o1.y * o1.y,
                    o0.z * o0.z + o1.z * o1.z, o0.w * o0.w + o1.w * o1.w);
    __syncthreads();
    tree_reduce_2x32(s_in, tid);
    if (tid < D) {
      atomicAdd(&st_sum[tid], s_in[tid]);
      atomicAdd(&st_sq[tid], s_in[32 * INP + tid]);
    }
  }

  if (EPI == 2) {
    // ---- Pool epilogue: <=2 graphs per 64-node block (sorted batch) ----
    int b0 = (node0 < N) ? batch[node0] : -1;
    int b1 = (node1 < N) ? batch[node1] : -1;
    int g_lo = batch[base];
    int g_hi = batch[min(base + NPB - 1, N - 1)];

    __syncthreads();   // s_in reads done; s_cnt init visible
    // ONLY q==0: the 16 q-lanes of an r2-group share the same two nodes.
    if (q == 0) {
      atomicAdd(&s_cnt[0], (b0 == g_lo ? 1 : 0) + (b1 == g_lo ? 1 : 0));
      if (g_hi != g_lo)
        atomicAdd(&s_cnt[1], (b0 == g_hi ? 1 : 0) + (b1 == g_hi ? 1 : 0));
    }

    float w0 = (b0 == g_lo) ? 1.f : 0.f;
    float w1 = (b1 == g_lo) ? 1.f : 0.f;
    *(float4*)&s_in[r2 * INP + q * 4] =
        make_float4(w0 * o0.x + w1 * o1.x, w0 * o0.y + w1 * o1.y,
                    w0 * o0.z + w1 * o1.z, w0 * o0.w + w1 * o1.w);
    *(float4*)&s_in[(32 + r2) * INP + q * 4] =
        make_float4(o0.x * o0.x + o1.x * o1.x, o0.y * o0.y + o1.y * o1.y,
                    o0.z * o0.z + o1.z * o1.z, o0.w * o0.w + o1.w * o1.w);
    __syncthreads();
    tree_reduce_2x32(s_in, tid);
    if (tid < D) {
      atomicAdd(&st_sum[g_lo * D + tid], s_in[tid]);
      atomicAdd(&st_sq[tid], s_in[32 * INP + tid]);
    }
    if (tid == 0) atomicAdd(&cnt[g_lo], (float)s_cnt[0]);

    if (g_hi != g_lo) {   // block-uniform branch
      __syncthreads();
      float u0 = (b0 == g_hi) ? 1.f : 0.f;
      float u1 = (b1 == g_hi) ? 1.f : 0.f;
      *(float4*)&s_in[r2 * INP + q * 4] =
          make_float4(u0 * o0.x + u1 * o1.x, u0 * o0.y + u1 * o1.y,
                      u0 * o0.z + u1 * o1.z, u0 * o0.w + u1 * o1.w);
      *(float4*)&s_in[(32 + r2) * INP + q * 4] = make_float4(0.f, 0.f, 0.f, 0.f);
      __syncthreads();
      tree_reduce_2x32(s_in, tid);
      if (tid < D) atomicAdd(&st_sum[g_hi * D + tid], s_in[tid]);
      if (tid == 0) atomicAdd(&cnt[g_hi], (float)s_cnt[1]);
    }
  }
}

// ---------------------------------------------------------------------------
// Final: BN2 coeffs from (Σ_g pool, sq) + fused affine + mean divide.
// ---------------------------------------------------------------------------
__global__ void final_kernel(const float* __restrict__ pool,
                             const float* __restrict__ cnt,
                             const float* __restrict__ sq,
                             const float* __restrict__ gamma,
                             const float* __restrict__ beta,
                             float invN, float* __restrict__ out) {
  int c = threadIdx.x;   // 64 threads
  float s = 0.f;
#pragma unroll
  for (int g = 0; g < NG; g++) s += pool[g * D + c];
  float mean = s * invN;
  float var = sq[c] * invN - mean * mean;
  float a = gamma[c] * rsqrtf(var + 1e-5f);
  float b = beta[c] - mean * a;
#pragma unroll
  for (int g = 0; g < NG; g++) {
    float n = cnt[g];
    out[g * D + c] = (a * pool[g * D + c] + n * b) / fmaxf(n, 1.f);
  }
}

extern "C" void kernel_launch(void* const* d_in, const int* in_sizes, int n_in,
                              void* d_out, int out_size, void* d_ws, size_t ws_size,
                              hipStream_t stream) {
  const float* x   = (const float*)d_in[0];
  const int* ei    = (const int*)d_in[1];
  const int* batch = (const int*)d_in[2];
  const float* W1a = (const float*)d_in[5];
  const float* b1a = (const float*)d_in[6];
  const float* W1b = (const float*)d_in[7];
  const float* b1b = (const float*)d_in[8];
  const float* g1  = (const float*)d_in[9];
  const float* be1 = (const float*)d_in[10];
  const float* W2a = (const float*)d_in[11];
  const float* b2a = (const float*)d_in[12];
  const float* W2b = (const float*)d_in[13];
  const float* b2b = (const float*)d_in[14];
  const float* g2  = (const float*)d_in[15];
  const float* be2 = (const float*)d_in[16];

  int N = in_sizes[0] / D;        // 100000
  int E = in_sizes[1] / 2;        // 1600000
  int per = E / NG;               // 100000
  int tmul = N / NG;              // 6250
  float invN = 1.f / (float)N;

  float* ws = (float*)d_ws;
  size_t ndh = (size_t)(N + 1) * D / 2;  // fp16 table size in floats (N+1 rows)
  float* h1h = ws;                       // h1 (pre-BN) fp16 table, N+1 rows
  float* xh  = ws + ndh;                 // x fp16 table, N+1 rows
  int*   col = (int*)(ws + 2 * ndh);     // CSR src lists (N*SLOT ints)
  float* stats = ws + 2 * ndh + (size_t)N * SLOT;
  float* sum1 = stats;                   // 64
  float* sq1  = stats + 64;              // 64
  float* pool = stats + 128;             // 16*64
  float* cnt  = stats + 128 + NG * D;    // 16
  float* sq2  = stats + 144 + NG * D;    // 64
  int*   fill = (int*)(stats + 208 + NG * D);  // N ints (degree counts)

  // Zero stats + fill (contiguous, ~0.4 MB) in one shot.
  hipMemsetAsync(stats, 0, (208 + NG * D + N) * sizeof(float), stream);

  // Fused prep: x->fp16 + pad-row zero + CSR build (n4 == E here).
  int n4 = N * D / 4;
  int pgrid = (max(n4, E) + 255) / 256;
  prep_kernel<<<pgrid, 256, 0, stream>>>(
      x, (float2*)xh, n4,
      (float4*)(xh + (size_t)N * D / 2),
      (float4*)(h1h + (size_t)N * D / 2),
      ei, fill, col, E, per, tmul);

  int fblocks = (N + NPB - 1) / NPB;   // 1563

  // Layer 1: gather(xh) + MLP1 -> h1h (fp16, pre-BN) + BN1-stats epilogue
  fused_layer_kernel<32, false, 1><<<fblocks, 512, 0, stream>>>(
      (const float4*)xh, col, fill, nullptr, nullptr, nullptr, nullptr, invN,
      W1a, b1a, W1b, b1b, (float2*)h1h, nullptr, sum1, sq1, nullptr, N);

  // Layer 2: BN1 folded into gather input; pool + sumsq epilogue (no h2)
  fused_layer_kernel<64, true, 2><<<fblocks, 512, 0, stream>>>(
      (const float4*)h1h, col, fill, sum1, sq1, g1, be1, invN,
      W2a, b2a, W2b, b2b, nullptr, batch, pool, sq2, cnt, N);

  // BN2 coeffs + affine + mean.
  final_kernel<<<1, 64, 0, stream>>>(pool, cnt, sq2, g2, be2, invN, (float*)d_out);
}